// Round 3
// baseline (590.320 us; speedup 1.0000x reference)
//
#include <hip/hip_runtime.h>
#include <cstdint>

// ---------------------------------------------------------------------------
// ConvModule: LN -> GEMM(512->1024)+SiLU -> conv K=5 (1024->1024) -> GLU ->
//             BN -> GEMM(512->512).  B=16, T=1024, C=512.
// Round 3: fp32 inputs/output (per reference dtypes); bf16 internal MFMA.
// ---------------------------------------------------------------------------

#define NB    16
#define TT    1024
#define CC    512
#define C2    1024
#define TPAD  1028        // T + 4 pad rows (2 each side) per batch
#define NTOK  16384       // B*T

typedef unsigned short u16;
typedef short bf16x8 __attribute__((ext_vector_type(8)));
typedef float f32x4  __attribute__((ext_vector_type(4)));

__device__ __forceinline__ float bf2f(u16 u) {
  union { unsigned int i; float f; } v; v.i = ((unsigned int)u) << 16; return v.f;
}
__device__ __forceinline__ u16 f2bf(float f) {
  union { float f; unsigned int i; } v; v.f = f;
  unsigned int x = v.i;
  return (u16)((x + 0x7fffu + ((x >> 16) & 1u)) >> 16);  // RNE
}

// ---------------------------------------------------------------------------
// fp32 -> bf16 elementwise convert (4 floats/thread)
__global__ __launch_bounds__(256) void cvt_f2b(
    const float* __restrict__ in, u16* __restrict__ out) {
  const int i = (blockIdx.x * 256 + threadIdx.x) * 4;
  float4 v = *(const float4*)(in + i);
  u16 o[4] = { f2bf(v.x), f2bf(v.y), f2bf(v.z), f2bf(v.w) };
  *(uint2*)(out + i) = *(const uint2*)o;
}

// ---------------------------------------------------------------------------
// zero the 4 pad rows per batch of h1p (B, TPAD, 2C) bf16
__global__ void zero_pads(u16* __restrict__ h1p) {
  const int idx = blockIdx.x * 256 + threadIdx.x;    // 8192 threads, 8 elems each
  const int bb  = idx >> 9;
  const int rem = idx & 511;
  const int ri  = rem >> 7;                          // 0..3
  const int c8  = (rem & 127) * 8;
  const int row = bb * TPAD + (ri < 2 ? ri : 1024 + ri);   // 0,1,1026,1027
  uint4 z = make_uint4(0u, 0u, 0u, 0u);
  *(uint4*)(h1p + (size_t)row * C2 + c8) = z;
}

// ---------------------------------------------------------------------------
// w2 fp32 (K, I, O) -> w2t bf16 (K, O, I)  (conv B-operand K-contiguous, B^T)
__global__ void transpose_w2(const float* __restrict__ w2, u16* __restrict__ w2t) {
  __shared__ u16 t[64][65];
  const int k  = blockIdx.z;
  const int i0 = blockIdx.x * 64, o0 = blockIdx.y * 64;
  const int tx = threadIdx.x, ty = threadIdx.y;
  for (int r = ty; r < 64; r += 4)
    t[r][tx] = f2bf(w2[((size_t)(k * C2) + i0 + r) * C2 + o0 + tx]);
  __syncthreads();
  for (int r = ty; r < 64; r += 4)
    w2t[((size_t)(k * C2) + o0 + r) * C2 + i0 + tx] = t[tx][r];
}

// ---------------------------------------------------------------------------
// LayerNorm over C=512 (fp32 in, bf16 out): one wave per token, 8 elems/lane
__global__ __launch_bounds__(256) void layernorm_k(
    const float* __restrict__ x, const float* __restrict__ lng,
    const float* __restrict__ lnb, u16* __restrict__ out) {
  const int tok  = blockIdx.x * 4 + (threadIdx.x >> 6);
  const int lane = threadIdx.x & 63;
  const float* xp = x + (size_t)tok * CC + lane * 8;
  float f[8];
  *(float4*)(f)     = *(const float4*)(xp);
  *(float4*)(f + 4) = *(const float4*)(xp + 4);
  float s = 0.f, s2 = 0.f;
#pragma unroll
  for (int j = 0; j < 8; j++) { s += f[j]; s2 += f[j] * f[j]; }
#pragma unroll
  for (int m = 32; m >= 1; m >>= 1) { s += __shfl_xor(s, m, 64); s2 += __shfl_xor(s2, m, 64); }
  const float mu  = s  * (1.f / 512.f);
  const float var = s2 * (1.f / 512.f) - mu * mu;
  const float rs  = rsqrtf(var + 1e-5f);
  u16 ov[8];
#pragma unroll
  for (int j = 0; j < 8; j++) {
    const int c = lane * 8 + j;
    ov[j] = f2bf((f[j] - mu) * rs * lng[c] + lnb[c]);
  }
  *(uint4*)(out + (size_t)tok * CC + lane * 8) = *(const uint4*)ov;
}

// ---------------------------------------------------------------------------
// GEMM  out[m,n] = sum_k A[m,k]*Bt[n,k] + bias[n]   (128x128x32 tile, bf16 in)
// EPI 0: +bias, SiLU, bf16 store to h1p at padded row (b*TPAD+t+2), ld=1024
// EPI 1: +bias, fp32 store to out ld=512
template <int EPI, typename OutT>
__global__ __launch_bounds__(256) void gemm_bt(
    const u16* __restrict__ A, const u16* __restrict__ Bt,
    const float* __restrict__ bias, OutT* __restrict__ out,
    const int Kd, const int ldA) {
  __shared__ __align__(16) u16 lsA[128 * 32];
  __shared__ __align__(16) u16 lsB[128 * 32];
  const int tid  = threadIdx.x;
  const int m0   = blockIdx.x * 128;
  const int n0   = blockIdx.y * 128;
  const int wave = tid >> 6, lane = tid & 63;
  const int wm = (wave & 1) * 64, wn = (wave >> 1) * 64;
  const int quad = lane >> 4, l16 = lane & 15;
  const int row = tid >> 2;            // 0..63 staging row
  const int kc  = (tid & 3) * 8;       // 0/8/16/24 staging col (elems)

  const u16* Ap = A  + (size_t)(m0 + row) * ldA + kc;
  const u16* Bp = Bt + (size_t)(n0 + row) * Kd  + kc;

  f32x4 acc[4][4] = {};
  uint4 ra0 = *(const uint4*)(Ap);
  uint4 ra1 = *(const uint4*)(Ap + (size_t)64 * ldA);
  uint4 rb0 = *(const uint4*)(Bp);
  uint4 rb1 = *(const uint4*)(Bp + (size_t)64 * Kd);

  for (int k0 = 0; k0 < Kd; k0 += 32) {
    __syncthreads();                       // prior iter done reading LDS
    *(uint4*)(lsA + tid * 8)        = ra0;
    *(uint4*)(lsA + 2048 + tid * 8) = ra1;
    *(uint4*)(lsB + tid * 8)        = rb0;
    *(uint4*)(lsB + 2048 + tid * 8) = rb1;
    __syncthreads();
    if (k0 + 32 < Kd) {                    // uniform branch: prefetch next chunk
      ra0 = *(const uint4*)(Ap + k0 + 32);
      ra1 = *(const uint4*)(Ap + (size_t)64 * ldA + k0 + 32);
      rb0 = *(const uint4*)(Bp + k0 + 32);
      rb1 = *(const uint4*)(Bp + (size_t)64 * Kd + k0 + 32);
    }
    bf16x8 af[4], bfr[4];
#pragma unroll
    for (int i = 0; i < 4; i++)
      af[i] = *(const bf16x8*)(lsA + (wm + i * 16 + l16) * 32 + quad * 8);
#pragma unroll
    for (int i = 0; i < 4; i++)
      bfr[i] = *(const bf16x8*)(lsB + (wn + i * 16 + l16) * 32 + quad * 8);
#pragma unroll
    for (int mi = 0; mi < 4; mi++)
#pragma unroll
      for (int ni = 0; ni < 4; ni++)
        acc[mi][ni] = __builtin_amdgcn_mfma_f32_16x16x32_bf16(af[mi], bfr[ni], acc[mi][ni], 0, 0, 0);
  }

#pragma unroll
  for (int mi = 0; mi < 4; mi++)
#pragma unroll
    for (int ni = 0; ni < 4; ni++) {
      const int cc = n0 + wn + ni * 16 + l16;
      const float bv = bias[cc];
#pragma unroll
      for (int r = 0; r < 4; r++) {
        const int rr = m0 + wm + mi * 16 + quad * 4 + r;   // D row = quad*4+reg
        float v = acc[mi][ni][r] + bv;
        if (EPI == 0) {
          v = v / (1.f + __expf(-v));                       // SiLU
          const int bb = rr >> 10, tt = rr & 1023;
          ((u16*)out)[(size_t)(bb * TPAD + tt + 2) * C2 + cc] = f2bf(v);
        } else {
          ((float*)out)[(size_t)rr * CC + cc] = v;
        }
      }
    }
}

// ---------------------------------------------------------------------------
// 5-tap conv as 5 accumulated GEMMs sharing one A-tile (132 rows staged, read
// with +k row shift).  A = h1p bf16 (padded), B = w2t[k] bf16 (O x I).
__global__ __launch_bounds__(256) void conv5_mfma(
    const u16* __restrict__ h1p, const u16* __restrict__ w2t,
    const float* __restrict__ b2, u16* __restrict__ out) {
  __shared__ __align__(16) u16 lsA[132 * 32];      // rows 0..131
  __shared__ __align__(16) u16 lsB[5 * 128 * 32];
  const int tid = threadIdx.x;
  const int mt  = blockIdx.x;                      // 0..127 row tile
  const int n0  = blockIdx.y * 128;
  const int bb  = mt >> 3;
  const int t0  = (mt & 7) * 128;
  const size_t arow0 = (size_t)bb * TPAD + t0;
  const int wave = tid >> 6, lane = tid & 63;
  const int wm = (wave & 1) * 64, wn = (wave >> 1) * 64;
  const int quad = lane >> 4, l16 = lane & 15;
  const int row = tid >> 2;
  const int kc  = (tid & 3) * 8;

  const u16* Ap  = h1p + (arow0 + row) * C2 + kc;            // rows row, row+64
  const u16* Ap3 = h1p + (arow0 + 128 + row) * C2 + kc;      // rows 128..131 (tid<16)

  f32x4 acc[4][4] = {};
  uint4 ra0, ra1, ra2, rb[5][2];
  ra0 = *(const uint4*)(Ap);
  ra1 = *(const uint4*)(Ap + (size_t)64 * C2);
  if (tid < 16) ra2 = *(const uint4*)(Ap3);
#pragma unroll
  for (int k = 0; k < 5; k++) {
    const u16* Bp = w2t + ((size_t)(k * C2 + n0 + row)) * C2 + kc;
    rb[k][0] = *(const uint4*)(Bp);
    rb[k][1] = *(const uint4*)(Bp + (size_t)64 * C2);
  }

  for (int i0 = 0; i0 < C2; i0 += 32) {
    __syncthreads();
    *(uint4*)(lsA + tid * 8)        = ra0;
    *(uint4*)(lsA + 2048 + tid * 8) = ra1;
    if (tid < 16) *(uint4*)(lsA + 4096 + tid * 8) = ra2;
#pragma unroll
    for (int k = 0; k < 5; k++) {
      *(uint4*)(lsB + k * 4096 + tid * 8)        = rb[k][0];
      *(uint4*)(lsB + k * 4096 + 2048 + tid * 8) = rb[k][1];
    }
    __syncthreads();
    if (i0 + 32 < C2) {                  // uniform: prefetch next K-chunk
      ra0 = *(const uint4*)(Ap + i0 + 32);
      ra1 = *(const uint4*)(Ap + (size_t)64 * C2 + i0 + 32);
      if (tid < 16) ra2 = *(const uint4*)(Ap3 + i0 + 32);
#pragma unroll
      for (int k = 0; k < 5; k++) {
        const u16* Bp = w2t + ((size_t)(k * C2 + n0 + row)) * C2 + kc + i0 + 32;
        rb[k][0] = *(const uint4*)(Bp);
        rb[k][1] = *(const uint4*)(Bp + (size_t)64 * C2);
      }
    }
#pragma unroll
    for (int k = 0; k < 5; k++) {
      bf16x8 af[4], bfr[4];
#pragma unroll
      for (int i = 0; i < 4; i++)
        af[i] = *(const bf16x8*)(lsA + (wm + i * 16 + l16 + k) * 32 + quad * 8);
#pragma unroll
      for (int i = 0; i < 4; i++)
        bfr[i] = *(const bf16x8*)(lsB + k * 4096 + (wn + i * 16 + l16) * 32 + quad * 8);
#pragma unroll
      for (int mi = 0; mi < 4; mi++)
#pragma unroll
        for (int ni = 0; ni < 4; ni++)
          acc[mi][ni] = __builtin_amdgcn_mfma_f32_16x16x32_bf16(af[mi], bfr[ni], acc[mi][ni], 0, 0, 0);
    }
  }

  const size_t orow0 = (size_t)bb * TT + t0;
#pragma unroll
  for (int mi = 0; mi < 4; mi++)
#pragma unroll
    for (int ni = 0; ni < 4; ni++) {
      const int cc = n0 + wn + ni * 16 + l16;
      const float bv = b2[cc];
#pragma unroll
      for (int r = 0; r < 4; r++) {
        const size_t rr = orow0 + wm + mi * 16 + quad * 4 + r;
        out[rr * C2 + cc] = f2bf(acc[mi][ni][r] + bv);
      }
    }
}

// ---------------------------------------------------------------------------
// GLU (a*sigmoid(g)) + BatchNorm(inference); bf16 in, fp32 params, bf16 out
__global__ __launch_bounds__(256) void glu_bn_k(
    const u16* __restrict__ hc, const float* __restrict__ bg,
    const float* __restrict__ bb_, const float* __restrict__ bm,
    const float* __restrict__ bv, u16* __restrict__ out) {
  const int idx = blockIdx.x * 256 + threadIdx.x;
  const int r  = idx >> 6;
  const int c8 = (idx & 63) * 8;
  const u16* pa = hc + (size_t)r * C2 + c8;
  uint4 ra = *(const uint4*)pa;
  uint4 rg = *(const uint4*)(pa + CC);
  u16 av[8], gv[8], ov[8];
  *(uint4*)av = ra; *(uint4*)gv = rg;
#pragma unroll
  for (int j = 0; j < 8; j++) {
    const int c = c8 + j;
    const float a = bf2f(av[j]);
    const float g = bf2f(gv[j]);
    const float h = a / (1.f + __expf(-g));
    const float sc = bg[c] * rsqrtf(bv[c] + 1e-5f);
    ov[j] = f2bf((h - bm[c]) * sc + bb_[c]);
  }
  *(uint4*)(out + (size_t)r * CC + c8) = *(const uint4*)ov;
}

// ---------------------------------------------------------------------------
extern "C" void kernel_launch(void* const* d_in, const int* in_sizes, int n_in,
                              void* d_out, int out_size, void* d_ws, size_t ws_size,
                              hipStream_t stream) {
  const float* x   = (const float*)d_in[0];
  const float* lng = (const float*)d_in[1];
  const float* lnb = (const float*)d_in[2];
  const float* w1  = (const float*)d_in[3];
  const float* b1  = (const float*)d_in[4];
  const float* w2  = (const float*)d_in[5];
  const float* b2  = (const float*)d_in[6];
  const float* bng = (const float*)d_in[7];
  const float* bnb = (const float*)d_in[8];
  const float* bnm = (const float*)d_in[9];
  const float* bnv = (const float*)d_in[10];
  const float* w3  = (const float*)d_in[11];
  const float* b3  = (const float*)d_in[12];
  float* out = (float*)d_out;

  // workspace layout (u16 elems): hln/h2 | h1p | w2t | hcv | w1b | w3b  (~96 MB)
  u16* ws  = (u16*)d_ws;
  u16* hln = ws;                               // 16384*512   = 8,388,608
  u16* h2  = hln;                              // alias (hln dead after GEMM1)
  u16* h1p = ws + 8388608;                     // 16*1028*1024 = 16,842,752
  u16* w2t = h1p + 16842752;                   // 5*1024*1024  = 5,242,880
  u16* hcv = w2t + 5242880;                    // 16384*1024   = 16,777,216
  u16* w1b = hcv + 16777216;                   // 1024*512     =   524,288
  u16* w3b = w1b + 524288;                     // 512*512      =   262,144

  zero_pads   <<<32, 256, 0, stream>>>(h1p);
  cvt_f2b     <<<512, 256, 0, stream>>>(w1, w1b);     // 524288/4/256
  cvt_f2b     <<<256, 256, 0, stream>>>(w3, w3b);     // 262144/4/256
  transpose_w2<<<dim3(16, 16, 5), dim3(64, 4), 0, stream>>>(w2, w2t);
  layernorm_k <<<4096, 256, 0, stream>>>(x, lng, lnb, hln);
  gemm_bt<0, u16>  <<<dim3(128, 8), 256, 0, stream>>>(hln, w1b, b1, h1p, 512, 512);
  conv5_mfma  <<<dim3(128, 8), 256, 0, stream>>>(h1p, w2t, b2, hcv);
  glu_bn_k    <<<4096, 256, 0, stream>>>(hcv, bng, bnb, bnm, bnv, h2);
  gemm_bt<1, float><<<dim3(128, 4), 256, 0, stream>>>(h2, w3b, b3, out, 512, 512);
}

// Round 4
// 504.165 us; speedup vs baseline: 1.1709x; 1.1709x over previous
//
#include <hip/hip_runtime.h>
#include <cstdint>

// ---------------------------------------------------------------------------
// ConvModule: LN -> GEMM(512->1024)+SiLU -> conv K=5 (1024->1024) -> GLU ->
//             BN -> GEMM(512->512).  B=16, T=1024, C=512. fp32 I/O, bf16 MFMA.
// Round 4: B-operands direct from global (L2-hot), A double-buffered in LDS
// (stride 40 = conflict-free), 1 barrier/iter, coalesced LDS-transpose
// epilogues (fixes 30x write amplification).
// ---------------------------------------------------------------------------

#define NB    16
#define TT    1024
#define CC    512
#define C2    1024
#define TPAD  1028        // T + 4 pad rows (2 each side) per batch

typedef unsigned short u16;
typedef short bf16x8 __attribute__((ext_vector_type(8)));
typedef float f32x4  __attribute__((ext_vector_type(4)));

__device__ __forceinline__ float bf2f(u16 u) {
  union { unsigned int i; float f; } v; v.i = ((unsigned int)u) << 16; return v.f;
}
__device__ __forceinline__ u16 f2bf(float f) {
  union { float f; unsigned int i; } v; v.f = f;
  unsigned int x = v.i;
  return (u16)((x + 0x7fffu + ((x >> 16) & 1u)) >> 16);  // RNE
}

// ---------------------------------------------------------------------------
__global__ __launch_bounds__(256) void cvt_f2b(
    const float* __restrict__ in, u16* __restrict__ out) {
  const int i = (blockIdx.x * 256 + threadIdx.x) * 4;
  float4 v = *(const float4*)(in + i);
  u16 o[4] = { f2bf(v.x), f2bf(v.y), f2bf(v.z), f2bf(v.w) };
  *(uint2*)(out + i) = *(const uint2*)o;
}

// ---------------------------------------------------------------------------
__global__ void zero_pads(u16* __restrict__ h1p) {
  const int idx = blockIdx.x * 256 + threadIdx.x;
  const int bb  = idx >> 9;
  const int rem = idx & 511;
  const int ri  = rem >> 7;
  const int c8  = (rem & 127) * 8;
  const int row = bb * TPAD + (ri < 2 ? ri : 1024 + ri);   // 0,1,1026,1027
  uint4 z = make_uint4(0u, 0u, 0u, 0u);
  *(uint4*)(h1p + (size_t)row * C2 + c8) = z;
}

// ---------------------------------------------------------------------------
// w2 fp32 (K, I, O) -> w2t bf16 (K, O, I)
__global__ void transpose_w2(const float* __restrict__ w2, u16* __restrict__ w2t) {
  __shared__ u16 t[64][65];
  const int k  = blockIdx.z;
  const int i0 = blockIdx.x * 64, o0 = blockIdx.y * 64;
  const int tx = threadIdx.x, ty = threadIdx.y;
  for (int r = ty; r < 64; r += 4)
    t[r][tx] = f2bf(w2[((size_t)(k * C2) + i0 + r) * C2 + o0 + tx]);
  __syncthreads();
  for (int r = ty; r < 64; r += 4)
    w2t[((size_t)(k * C2) + o0 + r) * C2 + i0 + tx] = t[tx][r];
}

// ---------------------------------------------------------------------------
__global__ __launch_bounds__(256) void layernorm_k(
    const float* __restrict__ x, const float* __restrict__ lng,
    const float* __restrict__ lnb, u16* __restrict__ out) {
  const int tok  = blockIdx.x * 4 + (threadIdx.x >> 6);
  const int lane = threadIdx.x & 63;
  const float* xp = x + (size_t)tok * CC + lane * 8;
  float f[8];
  *(float4*)(f)     = *(const float4*)(xp);
  *(float4*)(f + 4) = *(const float4*)(xp + 4);
  float s = 0.f, s2 = 0.f;
#pragma unroll
  for (int j = 0; j < 8; j++) { s += f[j]; s2 += f[j] * f[j]; }
#pragma unroll
  for (int m = 32; m >= 1; m >>= 1) { s += __shfl_xor(s, m, 64); s2 += __shfl_xor(s2, m, 64); }
  const float mu  = s  * (1.f / 512.f);
  const float var = s2 * (1.f / 512.f) - mu * mu;
  const float rs  = rsqrtf(var + 1e-5f);
  u16 ov[8];
#pragma unroll
  for (int j = 0; j < 8; j++) {
    const int c = lane * 8 + j;
    ov[j] = f2bf((f[j] - mu) * rs * lng[c] + lnb[c]);
  }
  *(uint4*)(out + (size_t)tok * CC + lane * 8) = *(const uint4*)ov;
}

// ---------------------------------------------------------------------------
// GEMM out[m,n] = sum_k A[m,k]*Bt[n,k] + bias[n].  128x128 tile, BK=32.
// A: LDS double-buffered (row stride 40 u16). B: direct global b128 frags.
// EPI 0: SiLU, bf16 -> h1p padded rows (ld C2).  EPI 1: fp32 -> out (ld CC).
template <int EPI>
__global__ __launch_bounds__(256) void gemm_bt(
    const u16* __restrict__ A, const u16* __restrict__ Bt,
    const float* __restrict__ bias, void* __restrict__ outv,
    const int Kd, const int ldA) {
  __shared__ __align__(16) u16 smem[18432];          // 36 KB: 2x5120 loop | 4x4608 epi
  const int tid  = threadIdx.x;
  const int m0   = blockIdx.x * 128;
  const int n0   = blockIdx.y * 128;
  const int wave = tid >> 6, lane = tid & 63;
  const int wm = (wave & 1) * 64, wn = (wave >> 1) * 64;
  const int quad = lane >> 4, l16 = lane & 15;
  const int row = tid >> 2;            // 0..63
  const int kc  = (tid & 3) * 8;       // 0/8/16/24

  const u16* Ap0 = A + (size_t)(m0 + row) * ldA + kc;
  const u16* Ap1 = Ap0 + (size_t)64 * ldA;
  const u16* Bb  = Bt + (size_t)(n0 + wn + l16) * Kd + quad * 8;  // + i*16*Kd + k0

  f32x4 acc[4][4] = {};
  uint4 rA0 = *(const uint4*)Ap0;
  uint4 rA1 = *(const uint4*)Ap1;
  { // prologue: fill buf0, prefetch chunk 1
    u16* b0 = smem;
    *(uint4*)(b0 + row * 40 + kc)        = rA0;
    *(uint4*)(b0 + (64 + row) * 40 + kc) = rA1;
  }
  rA0 = *(const uint4*)(Ap0 + 32);
  rA1 = *(const uint4*)(Ap1 + 32);

  for (int k0 = 0; k0 < Kd; k0 += 32) {
    __syncthreads();
    const u16* cur = smem + ((k0 >> 5) & 1) * 5120;
    if (k0 + 32 < Kd) {
      u16* nxt = smem + (((k0 >> 5) + 1) & 1) * 5120;
      *(uint4*)(nxt + row * 40 + kc)        = rA0;
      *(uint4*)(nxt + (64 + row) * 40 + kc) = rA1;
      if (k0 + 64 < Kd) {
        rA0 = *(const uint4*)(Ap0 + k0 + 64);
        rA1 = *(const uint4*)(Ap1 + k0 + 64);
      }
    }
    bf16x8 bfr[4], af[4];
#pragma unroll
    for (int i = 0; i < 4; i++)
      bfr[i] = *(const bf16x8*)(Bb + (size_t)i * 16 * Kd + k0);
#pragma unroll
    for (int i = 0; i < 4; i++)
      af[i] = *(const bf16x8*)(cur + (wm + i * 16 + l16) * 40 + quad * 8);
#pragma unroll
    for (int mi = 0; mi < 4; mi++)
#pragma unroll
      for (int ni = 0; ni < 4; ni++)
        acc[mi][ni] = __builtin_amdgcn_mfma_f32_16x16x32_bf16(af[mi], bfr[ni], acc[mi][ni], 0, 0, 0);
  }
  __syncthreads();                       // loop LDS dead; epi regions are private

  float bv[4];
#pragma unroll
  for (int ni = 0; ni < 4; ni++) bv[ni] = bias[n0 + wn + ni * 16 + l16];

  if (EPI == 0) {
    u16* epi = smem + wave * 4608;       // 64 x 72 u16
#pragma unroll
    for (int mi = 0; mi < 4; mi++)
#pragma unroll
      for (int ni = 0; ni < 4; ni++)
#pragma unroll
        for (int r = 0; r < 4; r++) {
          float v = acc[mi][ni][r] + bv[ni];
          v = v / (1.f + __expf(-v));    // SiLU
          epi[(mi * 16 + quad * 4 + r) * 72 + ni * 16 + l16] = f2bf(v);
        }
    u16* h1p = (u16*)outv;
#pragma unroll
    for (int p = 0; p < 8; p++) {
      const int rrow = p * 8 + (lane >> 3);
      const int colb = (lane & 7) * 8;
      uint4 v = *(const uint4*)(epi + rrow * 72 + colb);
      const int rr = m0 + wm + rrow;
      const int bb = rr >> 10, tt = rr & 1023;
      *(uint4*)(h1p + (size_t)(bb * TPAD + tt + 2) * C2 + n0 + wn + colb) = v;
    }
  } else {
    float* fepi = (float*)(smem + wave * 4608);     // 2 x (16 x 68) f32 halves
    float* outf = (float*)outv;
#pragma unroll
    for (int mi = 0; mi < 4; mi++) {
      float* fp = fepi + (mi & 1) * 1088;
#pragma unroll
      for (int ni = 0; ni < 4; ni++)
#pragma unroll
        for (int r = 0; r < 4; r++)
          fp[(quad * 4 + r) * 68 + ni * 16 + l16] = acc[mi][ni][r] + bv[ni];
#pragma unroll
      for (int p = 0; p < 4; p++) {
        const int rrow = p * 4 + (lane >> 4);
        const int col  = (lane & 15) * 4;
        float4 v = *(const float4*)(fp + rrow * 68 + col);
        *(float4*)(outf + (size_t)(m0 + wm + mi * 16 + rrow) * CC + n0 + wn + col) = v;
      }
    }
  }
}

// ---------------------------------------------------------------------------
// 5-tap conv: A (h1p, padded) staged 132x32 double-buffered in LDS; B frags
// (w2t, L2-hot) loaded direct from global with tap pipelining; 80 MFMA/iter.
__global__ __launch_bounds__(256) void conv5_mfma(
    const u16* __restrict__ h1p, const u16* __restrict__ w2t,
    const float* __restrict__ b2, u16* __restrict__ out) {
  __shared__ __align__(16) u16 smem[18432];          // 2x5280 loop | 4x4608 epi
  const int tid = threadIdx.x;
  const int mt  = blockIdx.x;
  const int n0  = blockIdx.y * 128;
  const int bb  = mt >> 3;
  const int t0  = (mt & 7) * 128;
  const size_t arow0 = (size_t)bb * TPAD + t0;
  const int wave = tid >> 6, lane = tid & 63;
  const int wm = (wave & 1) * 64, wn = (wave >> 1) * 64;
  const int quad = lane >> 4, l16 = lane & 15;
  const int row = tid >> 2;
  const int kc  = (tid & 3) * 8;

  const u16* Ap0 = h1p + (arow0 + row) * C2 + kc;
  const u16* Ap1 = Ap0 + (size_t)64 * C2;
  const u16* Ap2 = h1p + (arow0 + 128 + row) * C2 + kc;     // tid<16: rows 128..131
  const u16* Bb  = w2t + (size_t)(n0 + wn + l16) * C2 + quad * 8;  // +k*C2*C2 +i*16*C2 +i0

  f32x4 acc[4][4] = {};
  uint4 rA0 = *(const uint4*)Ap0;
  uint4 rA1 = *(const uint4*)Ap1;
  uint4 rA2;
  if (tid < 16) rA2 = *(const uint4*)Ap2;
  { // prologue: fill buf0, prefetch chunk 1
    u16* b0 = smem;
    *(uint4*)(b0 + row * 40 + kc)         = rA0;
    *(uint4*)(b0 + (64 + row) * 40 + kc)  = rA1;
    if (tid < 16) *(uint4*)(b0 + (128 + row) * 40 + kc) = rA2;
  }
  rA0 = *(const uint4*)(Ap0 + 32);
  rA1 = *(const uint4*)(Ap1 + 32);
  if (tid < 16) rA2 = *(const uint4*)(Ap2 + 32);

  for (int i0 = 0; i0 < C2; i0 += 32) {
    __syncthreads();
    const u16* cur = smem + ((i0 >> 5) & 1) * 5280;
    if (i0 + 32 < C2) {
      u16* nxt = smem + (((i0 >> 5) + 1) & 1) * 5280;
      *(uint4*)(nxt + row * 40 + kc)        = rA0;
      *(uint4*)(nxt + (64 + row) * 40 + kc) = rA1;
      if (tid < 16) *(uint4*)(nxt + (128 + row) * 40 + kc) = rA2;
      if (i0 + 64 < C2) {
        rA0 = *(const uint4*)(Ap0 + i0 + 64);
        rA1 = *(const uint4*)(Ap1 + i0 + 64);
        if (tid < 16) rA2 = *(const uint4*)(Ap2 + i0 + 64);
      }
    }
    const u16* Bt0 = Bb + i0;
    bf16x8 bnxt[4], bcur[4];
#pragma unroll
    for (int i = 0; i < 4; i++)
      bnxt[i] = *(const bf16x8*)(Bt0 + (size_t)i * 16 * C2);
#pragma unroll
    for (int k = 0; k < 5; k++) {
#pragma unroll
      for (int i = 0; i < 4; i++) bcur[i] = bnxt[i];
      if (k < 4) {
        const u16* Btk = Bt0 + (size_t)(k + 1) * C2 * C2;
#pragma unroll
        for (int i = 0; i < 4; i++)
          bnxt[i] = *(const bf16x8*)(Btk + (size_t)i * 16 * C2);
      }
      bf16x8 af[4];
#pragma unroll
      for (int i = 0; i < 4; i++)
        af[i] = *(const bf16x8*)(cur + (wm + i * 16 + l16 + k) * 40 + quad * 8);
#pragma unroll
      for (int mi = 0; mi < 4; mi++)
#pragma unroll
        for (int ni = 0; ni < 4; ni++)
          acc[mi][ni] = __builtin_amdgcn_mfma_f32_16x16x32_bf16(af[mi], bcur[ni], acc[mi][ni], 0, 0, 0);
    }
  }
  __syncthreads();

  float bv[4];
#pragma unroll
  for (int ni = 0; ni < 4; ni++) bv[ni] = b2[n0 + wn + ni * 16 + l16];

  u16* epi = smem + wave * 4608;         // 64 x 72 u16, private per wave
#pragma unroll
  for (int mi = 0; mi < 4; mi++)
#pragma unroll
    for (int ni = 0; ni < 4; ni++)
#pragma unroll
      for (int r = 0; r < 4; r++)
        epi[(mi * 16 + quad * 4 + r) * 72 + ni * 16 + l16] = f2bf(acc[mi][ni][r] + bv[ni]);

  const size_t orow0 = (size_t)bb * TT + t0;
#pragma unroll
  for (int p = 0; p < 8; p++) {
    const int rrow = p * 8 + (lane >> 3);
    const int colb = (lane & 7) * 8;
    uint4 v = *(const uint4*)(epi + rrow * 72 + colb);
    *(uint4*)(out + (orow0 + wm + rrow) * C2 + n0 + wn + colb) = v;
  }
}

// ---------------------------------------------------------------------------
__global__ __launch_bounds__(256) void glu_bn_k(
    const u16* __restrict__ hc, const float* __restrict__ bg,
    const float* __restrict__ bb_, const float* __restrict__ bm,
    const float* __restrict__ bv, u16* __restrict__ out) {
  const int idx = blockIdx.x * 256 + threadIdx.x;
  const int r  = idx >> 6;
  const int c8 = (idx & 63) * 8;
  const u16* pa = hc + (size_t)r * C2 + c8;
  uint4 ra = *(const uint4*)pa;
  uint4 rg = *(const uint4*)(pa + CC);
  u16 av[8], gv[8], ov[8];
  *(uint4*)av = ra; *(uint4*)gv = rg;
#pragma unroll
  for (int j = 0; j < 8; j++) {
    const int c = c8 + j;
    const float a = bf2f(av[j]);
    const float g = bf2f(gv[j]);
    const float h = a / (1.f + __expf(-g));
    const float sc = bg[c] * rsqrtf(bv[c] + 1e-5f);
    ov[j] = f2bf((h - bm[c]) * sc + bb_[c]);
  }
  *(uint4*)(out + (size_t)r * CC + c8) = *(const uint4*)ov;
}

// ---------------------------------------------------------------------------
extern "C" void kernel_launch(void* const* d_in, const int* in_sizes, int n_in,
                              void* d_out, int out_size, void* d_ws, size_t ws_size,
                              hipStream_t stream) {
  const float* x   = (const float*)d_in[0];
  const float* lng = (const float*)d_in[1];
  const float* lnb = (const float*)d_in[2];
  const float* w1  = (const float*)d_in[3];
  const float* b1  = (const float*)d_in[4];
  const float* w2  = (const float*)d_in[5];
  const float* b2  = (const float*)d_in[6];
  const float* bng = (const float*)d_in[7];
  const float* bnb = (const float*)d_in[8];
  const float* bnm = (const float*)d_in[9];
  const float* bnv = (const float*)d_in[10];
  const float* w3  = (const float*)d_in[11];
  const float* b3  = (const float*)d_in[12];

  u16* ws  = (u16*)d_ws;
  u16* hln = ws;                               // 16384*512
  u16* h2  = hln;                              // alias (hln dead after GEMM1)
  u16* h1p = ws + 8388608;                     // 16*1028*1024
  u16* w2t = h1p + 16842752;                   // 5*1024*1024
  u16* hcv = w2t + 5242880;                    // 16384*1024
  u16* w1b = hcv + 16777216;                   // 1024*512
  u16* w3b = w1b + 524288;                     // 512*512

  zero_pads   <<<32, 256, 0, stream>>>(h1p);
  cvt_f2b     <<<512, 256, 0, stream>>>(w1, w1b);
  cvt_f2b     <<<256, 256, 0, stream>>>(w3, w3b);
  transpose_w2<<<dim3(16, 16, 5), dim3(64, 4), 0, stream>>>(w2, w2t);
  layernorm_k <<<4096, 256, 0, stream>>>(x, lng, lnb, hln);
  gemm_bt<0>  <<<dim3(128, 8), 256, 0, stream>>>(hln, w1b, b1, h1p, 512, 512);
  conv5_mfma  <<<dim3(128, 8), 256, 0, stream>>>(h1p, w2t, b2, hcv);
  glu_bn_k    <<<4096, 256, 0, stream>>>(hcv, bng, bnb, bnm, bnv, h2);
  gemm_bt<1>  <<<dim3(128, 4), 256, 0, stream>>>(h2, w3b, b3, d_out, 512, 512);
}